// Round 2
// baseline (726.968 us; speedup 1.0000x reference)
//
#include <hip/hip_runtime.h>

// HyperGAT layer, N=16384, E=4096, D=256 on gfx950.
// Exponent-sensitive values (c_j, d_n, f2) computed to ~fp32 accuracy via
// compensated bf16 hi/lo splits; output path stays plain bf16.
//   xw1 = x@w1                         (split-bf16 MFMA: Ah*Bh + Ah*Bl + Al*Bh)
//   g_n = satexp(leaky(xw1)@a1), d_n = leaky(xw1)@a22
//   yT[0:256]=hi(g*xw1), yT[256]=hi(g), yT[288:544]=lo(g*xw1), yT[544]=lo(g)
//   C1[j,:] = H^T @ yT^T               (bf16 GEMM, H exact; hi+lo cols summed)
//   f2 = leaky(C1[:,0:256]/C1[:,256]);  G = f2@w2 (split);  c_j = leaky(G)@a21
//   Bmat[n,j] = H[n,j]*satexp(c_j+d_n) bf16; rowsum from rounded values
//   out = leaky((Bmat@G)/rowsum)

typedef __attribute__((ext_vector_type(8))) short short8;
typedef __attribute__((ext_vector_type(4))) short short4v;
typedef __attribute__((ext_vector_type(4))) float f32x4;

__device__ __forceinline__ float leakyf(float v) { return v > 0.f ? v : 0.1f * v; }
__device__ __forceinline__ float fastrcp(float x) { return __builtin_amdgcn_rcpf(x); }

// exp(8*tanh(t/8)), branchless, overflow-safe (tanh via e^{t/4})
__device__ __forceinline__ float satexpf(float t) {
    float u = fminf(fmaxf(t * 0.25f, -30.f), 30.f);
    float p = __expf(u);                       // e^{t/4}
    float th = (p - 1.f) * fastrcp(p + 1.f);   // tanh(t/8)
    return __expf(8.f * th);
}

// fp32 -> bf16 RNE, as raw short
__device__ __forceinline__ short f2b(float v) {
    unsigned int x = __float_as_uint(v);
    x += 0x7fffu + ((x >> 16) & 1u);
    return (short)(x >> 16);
}
// bf16 (raw short) -> fp32
__device__ __forceinline__ float b2f(short s) {
    return __uint_as_float(((unsigned int)(unsigned short)s) << 16);
}

// ---------------------------------------------------------------- transpose (plain, for H)
__global__ __launch_bounds__(256) void transpose_f32_bf16(
        const float* __restrict__ src, short* __restrict__ dst, int R, int C) {
    __shared__ float Ts[64][65];
    const int t = threadIdx.x;
    const long r0 = (long)blockIdx.x * 64;
    const long c0 = (long)blockIdx.y * 64;
    {
        const int row = t >> 2, cc = (t & 3) * 16;
        const float* p = src + (r0 + row) * (long)C + c0 + cc;
#pragma unroll
        for (int i = 0; i < 4; ++i) {
            f32x4 v = *reinterpret_cast<const f32x4*>(p + i * 4);
#pragma unroll
            for (int k = 0; k < 4; ++k) Ts[row][cc + i * 4 + k] = v[k];
        }
    }
    __syncthreads();
    {
        const int cl = t >> 2, ch = (t & 3) * 16;
        short8 pk0, pk1;
#pragma unroll
        for (int i = 0; i < 8; ++i) pk0[i] = f2b(Ts[ch + i][cl]);
#pragma unroll
        for (int i = 0; i < 8; ++i) pk1[i] = f2b(Ts[ch + 8 + i][cl]);
        short* q = dst + (c0 + cl) * (long)R + r0 + ch;
        *reinterpret_cast<short8*>(q) = pk0;
        *reinterpret_cast<short8*>(q + 8) = pk1;
    }
}

// ---------------------------------------------------------------- transpose with hi/lo split (weights)
__global__ __launch_bounds__(256) void transpose_split(
        const float* __restrict__ src, short* __restrict__ dh,
        short* __restrict__ dl, int R, int C) {
    __shared__ float Ts[64][65];
    const int t = threadIdx.x;
    const long r0 = (long)blockIdx.x * 64;
    const long c0 = (long)blockIdx.y * 64;
    {
        const int row = t >> 2, cc = (t & 3) * 16;
        const float* p = src + (r0 + row) * (long)C + c0 + cc;
#pragma unroll
        for (int i = 0; i < 4; ++i) {
            f32x4 v = *reinterpret_cast<const f32x4*>(p + i * 4);
#pragma unroll
            for (int k = 0; k < 4; ++k) Ts[row][cc + i * 4 + k] = v[k];
        }
    }
    __syncthreads();
    {
        const int cl = t >> 2, ch = (t & 3) * 16;
        short8 h0, h1, l0, l1;
#pragma unroll
        for (int i = 0; i < 8; ++i) {
            float v = Ts[ch + i][cl];
            short h = f2b(v);
            h0[i] = h; l0[i] = f2b(v - b2f(h));
        }
#pragma unroll
        for (int i = 0; i < 8; ++i) {
            float v = Ts[ch + 8 + i][cl];
            short h = f2b(v);
            h1[i] = h; l1[i] = f2b(v - b2f(h));
        }
        short* qh = dh + (c0 + cl) * (long)R + r0 + ch;
        short* ql = dl + (c0 + cl) * (long)R + r0 + ch;
        *reinterpret_cast<short8*>(qh) = h0;
        *reinterpret_cast<short8*>(qh + 8) = h1;
        *reinterpret_cast<short8*>(ql) = l0;
        *reinterpret_cast<short8*>(ql + 8) = l1;
    }
}

// ---------------------------------------------------------------- xw1 split GEMM
// C[16384,256] fp32 = x[16384,256] @ w1; A fp32 split on the fly, B pre-split.
__global__ __launch_bounds__(256) void gemm_xw1(
        const float* __restrict__ A, const short* __restrict__ Bh,
        const short* __restrict__ Bl, float* __restrict__ C) {
    __shared__ short Ash[128][72];
    __shared__ short Asl[128][72];
    __shared__ short Bsh[64][72];
    __shared__ short Bsl[64][72];
    const int t = threadIdx.x;
    const int wid = t >> 6, lane = t & 63;
    const int wm = wid & 1, wn = wid >> 1;
    const int quad = lane >> 4, l15 = lane & 15;
    const long m0 = (long)blockIdx.x * 128;
    const long n0 = (long)blockIdx.y * 64;
    f32x4 acc[4][2];
#pragma unroll
    for (int i = 0; i < 4; ++i)
#pragma unroll
        for (int j = 0; j < 2; ++j)
#pragma unroll
            for (int r = 0; r < 4; ++r) acc[i][j][r] = 0.f;

    for (int kb = 0; kb < 256; kb += 64) {
#pragma unroll
        for (int it = 0; it < 4; ++it) {
            const int cid = t + it * 256;
            const int row = cid >> 3, c8 = (cid & 7) * 8;
            const float* ap = A + (m0 + row) * 256 + kb + c8;
            f32x4 v0 = *reinterpret_cast<const f32x4*>(ap);
            f32x4 v1 = *reinterpret_cast<const f32x4*>(ap + 4);
            short8 hi, lo;
#pragma unroll
            for (int k = 0; k < 4; ++k) {
                short h0 = f2b(v0[k]); hi[k] = h0; lo[k] = f2b(v0[k] - b2f(h0));
                short h1 = f2b(v1[k]); hi[4 + k] = h1; lo[4 + k] = f2b(v1[k] - b2f(h1));
            }
            *reinterpret_cast<short8*>(&Ash[row][c8]) = hi;
            *reinterpret_cast<short8*>(&Asl[row][c8]) = lo;
        }
#pragma unroll
        for (int it = 0; it < 2; ++it) {
            const int cid = t + it * 256;
            const int row = cid >> 3, c8 = (cid & 7) * 8;
            *reinterpret_cast<short8*>(&Bsh[row][c8]) =
                *reinterpret_cast<const short8*>(Bh + (n0 + row) * 256 + kb + c8);
            *reinterpret_cast<short8*>(&Bsl[row][c8]) =
                *reinterpret_cast<const short8*>(Bl + (n0 + row) * 256 + kb + c8);
        }
        __syncthreads();
#pragma unroll
        for (int ks = 0; ks < 2; ++ks) {
            short8 ah[4], al[4], bh[2], bl[2];
#pragma unroll
            for (int i = 0; i < 4; ++i) {
                ah[i] = *reinterpret_cast<const short8*>(&Ash[wm * 64 + i * 16 + l15][ks * 32 + quad * 8]);
                al[i] = *reinterpret_cast<const short8*>(&Asl[wm * 64 + i * 16 + l15][ks * 32 + quad * 8]);
            }
#pragma unroll
            for (int j = 0; j < 2; ++j) {
                bh[j] = *reinterpret_cast<const short8*>(&Bsh[wn * 32 + j * 16 + l15][ks * 32 + quad * 8]);
                bl[j] = *reinterpret_cast<const short8*>(&Bsl[wn * 32 + j * 16 + l15][ks * 32 + quad * 8]);
            }
#pragma unroll
            for (int i = 0; i < 4; ++i)
#pragma unroll
                for (int j = 0; j < 2; ++j) {
                    acc[i][j] = __builtin_amdgcn_mfma_f32_16x16x32_bf16(ah[i], bh[j], acc[i][j], 0, 0, 0);
                    acc[i][j] = __builtin_amdgcn_mfma_f32_16x16x32_bf16(ah[i], bl[j], acc[i][j], 0, 0, 0);
                    acc[i][j] = __builtin_amdgcn_mfma_f32_16x16x32_bf16(al[i], bh[j], acc[i][j], 0, 0, 0);
                }
        }
        __syncthreads();
    }
#pragma unroll
    for (int i = 0; i < 4; ++i) {
        const long grow = m0 + wm * 64 + i * 16 + quad * 4;
#pragma unroll
        for (int j = 0; j < 2; ++j) {
            const long gcol = n0 + wn * 32 + j * 16 + l15;
#pragma unroll
            for (int r = 0; r < 4; ++r)
                C[(grow + r) * 256 + gcol] = acc[i][j][r];
        }
    }
}

// ---------------------------------------------------------------- node stats
// reads xw1 fp32 [16384,256]; writes yT bf16 [576,16384]:
//   rows 0..255 hi(g*xw1), 256 hi(g), 257..287 zero,
//   rows 288..543 lo(g*xw1), 544 lo(g), 545..575 zero;  dn fp32 [16384].
__global__ __launch_bounds__(256) void node_stats(
        const float* __restrict__ xw1, const float* __restrict__ a1,
        const float* __restrict__ a22, short* __restrict__ yT,
        float* __restrict__ dn) {
    __shared__ short Ys[257][72];
    const int t = threadIdx.x;
    const int n0 = blockIdx.x * 64;
    const int r = t >> 2, q = t & 3;
    const long n = n0 + r;
    const float* xp = xw1 + n * 256 + q * 64;
    float vals[64];
    float facc = 0.f, dacc = 0.f;
#pragma unroll
    for (int i = 0; i < 16; ++i) {
        f32x4 v  = *reinterpret_cast<const f32x4*>(xp + i * 4);
        f32x4 b1 = *reinterpret_cast<const f32x4*>(a1 + q * 64 + i * 4);
        f32x4 b2 = *reinterpret_cast<const f32x4*>(a22 + q * 64 + i * 4);
#pragma unroll
        for (int k = 0; k < 4; ++k) {
            float lv = leakyf(v[k]);
            facc += lv * b1[k];
            dacc += lv * b2[k];
            vals[i * 4 + k] = v[k];
        }
    }
    facc += __shfl_xor(facc, 1); facc += __shfl_xor(facc, 2);
    dacc += __shfl_xor(dacc, 1); dacc += __shfl_xor(dacc, 2);
    const float g = satexpf(facc);
    const int dr = t >> 3, c8 = (t & 7) * 8;
    // ---- phase A: hi ----
    if (q == 0) { dn[n] = dacc; Ys[256][r] = f2b(g); }
#pragma unroll
    for (int i = 0; i < 64; ++i) Ys[q * 64 + i][r] = f2b(vals[i] * g);
    __syncthreads();
    for (int it = 0; it < 9; ++it) {
        const int d = it * 32 + dr;
        short8 pk;
        if (d <= 256) pk = *reinterpret_cast<const short8*>(&Ys[d][c8]);
        else { short8 z = {0,0,0,0,0,0,0,0}; pk = z; }
        *reinterpret_cast<short8*>(yT + (long)d * 16384 + n0 + c8) = pk;
    }
    __syncthreads();
    // ---- phase B: lo ----
    if (q == 0) Ys[256][r] = f2b(g - b2f(f2b(g)));
#pragma unroll
    for (int i = 0; i < 64; ++i) {
        float yv = vals[i] * g;
        Ys[q * 64 + i][r] = f2b(yv - b2f(f2b(yv)));
    }
    __syncthreads();
    for (int it = 0; it < 9; ++it) {
        const int d = it * 32 + dr;
        short8 pk;
        if (d <= 256) pk = *reinterpret_cast<const short8*>(&Ys[d][c8]);
        else { short8 z = {0,0,0,0,0,0,0,0}; pk = z; }
        *reinterpret_cast<short8*>(yT + (long)(288 + d) * 16384 + n0 + c8) = pk;
    }
}

// ---------------------------------------------------------------- main GEMM
// C[M,N] = A[M,K] * B[N,K]^T, bf16 MFMA 16x16x32, BK=64, 256 threads (4 waves).
// EPI 0: C = v; 2: C = leaky(v / aux[row]).
template<int BM, int BN, int EPI>
__global__ __launch_bounds__(256) void gemm_bt(
        const short* __restrict__ Ab, const short* __restrict__ Bb,
        float* __restrict__ C, long ldA, long ldB, long ldC,
        int Ktile, const float* __restrict__ aux, long zstrideC) {
    constexpr int BK = 64;
    constexpr int TM = BM / 32, TN = BN / 32;
    __shared__ short As[BM][BK + 8];
    __shared__ short Bs[BN][BK + 8];
    const int t = threadIdx.x;
    const int wid = t >> 6, lane = t & 63;
    const int wm = wid & 1, wn = wid >> 1;
    const int quad = lane >> 4, l15 = lane & 15;
    const long m0 = (long)blockIdx.x * BM;
    const long n0 = (long)blockIdx.y * BN;
    const long k0 = (long)blockIdx.z * Ktile;
    float* Cz = C + (long)blockIdx.z * zstrideC;

    f32x4 acc[TM][TN];
#pragma unroll
    for (int i = 0; i < TM; ++i)
#pragma unroll
        for (int j = 0; j < TN; ++j)
#pragma unroll
            for (int r = 0; r < 4; ++r) acc[i][j][r] = 0.f;

    for (int kb = 0; kb < Ktile; kb += BK) {
#pragma unroll
        for (int it = 0; it < BM * BK / 2048; ++it) {
            const int cid = t + it * 256;
            const int row = cid >> 3, c8 = (cid & 7) * 8;
            *reinterpret_cast<short8*>(&As[row][c8]) =
                *reinterpret_cast<const short8*>(Ab + (m0 + row) * ldA + k0 + kb + c8);
        }
#pragma unroll
        for (int it = 0; it < BN * BK / 2048; ++it) {
            const int cid = t + it * 256;
            const int row = cid >> 3, c8 = (cid & 7) * 8;
            *reinterpret_cast<short8*>(&Bs[row][c8]) =
                *reinterpret_cast<const short8*>(Bb + (n0 + row) * ldB + k0 + kb + c8);
        }
        __syncthreads();
#pragma unroll
        for (int ks = 0; ks < 2; ++ks) {
            short8 af[TM], bf[TN];
#pragma unroll
            for (int i = 0; i < TM; ++i)
                af[i] = *reinterpret_cast<const short8*>(
                        &As[wm * (BM / 2) + i * 16 + l15][ks * 32 + quad * 8]);
#pragma unroll
            for (int j = 0; j < TN; ++j)
                bf[j] = *reinterpret_cast<const short8*>(
                        &Bs[wn * (BN / 2) + j * 16 + l15][ks * 32 + quad * 8]);
#pragma unroll
            for (int i = 0; i < TM; ++i)
#pragma unroll
                for (int j = 0; j < TN; ++j)
                    acc[i][j] = __builtin_amdgcn_mfma_f32_16x16x32_bf16(
                            af[i], bf[j], acc[i][j], 0, 0, 0);
        }
        __syncthreads();
    }
#pragma unroll
    for (int i = 0; i < TM; ++i) {
        const long grow = m0 + wm * (BM / 2) + i * 16 + quad * 4;
#pragma unroll
        for (int j = 0; j < TN; ++j) {
            const long gcol = n0 + wn * (BN / 2) + j * 16 + l15;
#pragma unroll
            for (int r = 0; r < 4; ++r) {
                const float v = acc[i][j][r];
                float* cp = Cz + (grow + r) * ldC + gcol;
                if (EPI == 0) *cp = v;
                else *cp = leakyf(v * fastrcp(aux[grow + r]));
            }
        }
    }
}

// ---------------------------------------------------------------- reduce split-K partials + hi/lo halves
// C1p [4][4096][576] -> C1 [4096][288]
__global__ __launch_bounds__(256) void reduce_C1(
        const float* __restrict__ C1p, float* __restrict__ C1) {
    const int i = blockIdx.x * 256 + threadIdx.x;  // < 4096*288
    const int j = i / 288, dd = i - j * 288;
    const float* p = C1p + (long)j * 576 + dd;
    float s = 0.f;
#pragma unroll
    for (int z = 0; z < 4; ++z) {
        const float* pz = p + (long)z * 4096 * 576;
        s += pz[0] + pz[288];
    }
    C1[i] = s;
}

// ---------------------------------------------------------------- G = f2@w2 split (+ GT bf16, c_j)
__global__ __launch_bounds__(256) void gemm_G(
        const float* __restrict__ C1, const short* __restrict__ w2Th,
        const short* __restrict__ w2Tl, const float* __restrict__ a21,
        short* __restrict__ GT, float* __restrict__ cat) {
    __shared__ short Ash[64][72];
    __shared__ short Asl[64][72];
    __shared__ short Bsh[64][72];
    __shared__ short Bsl[64][72];
    __shared__ float Gs[64][65];
    const int t = threadIdx.x;
    const int wid = t >> 6, lane = t & 63;
    const int wm = wid & 1, wn = wid >> 1;
    const int quad = lane >> 4, l15 = lane & 15;
    const long j0 = (long)blockIdx.x * 64;
    const long d0 = (long)blockIdx.y * 64;
    f32x4 acc[2][2];
#pragma unroll
    for (int i = 0; i < 2; ++i)
#pragma unroll
        for (int j = 0; j < 2; ++j)
#pragma unroll
            for (int r = 0; r < 4; ++r) acc[i][j][r] = 0.f;

    for (int kb = 0; kb < 256; kb += 64) {
#pragma unroll
        for (int it = 0; it < 2; ++it) {
            const int cid = t + it * 256;
            const int row = cid >> 3, c8 = (cid & 7) * 8;
            const float rd = fastrcp(C1[(j0 + row) * 288 + 256]);
            const float* ap = C1 + (j0 + row) * 288 + kb + c8;
            f32x4 v0 = *reinterpret_cast<const f32x4*>(ap);
            f32x4 v1 = *reinterpret_cast<const f32x4*>(ap + 4);
            short8 hi, lo;
#pragma unroll
            for (int k = 0; k < 4; ++k) {
                float f0 = leakyf(v0[k] * rd);
                float f1 = leakyf(v1[k] * rd);
                short h0 = f2b(f0); hi[k] = h0; lo[k] = f2b(f0 - b2f(h0));
                short h1 = f2b(f1); hi[4 + k] = h1; lo[4 + k] = f2b(f1 - b2f(h1));
            }
            *reinterpret_cast<short8*>(&Ash[row][c8]) = hi;
            *reinterpret_cast<short8*>(&Asl[row][c8]) = lo;
            *reinterpret_cast<short8*>(&Bsh[row][c8]) =
                *reinterpret_cast<const short8*>(w2Th + (d0 + row) * 256 + kb + c8);
            *reinterpret_cast<short8*>(&Bsl[row][c8]) =
                *reinterpret_cast<const short8*>(w2Tl + (d0 + row) * 256 + kb + c8);
        }
        __syncthreads();
#pragma unroll
        for (int ks = 0; ks < 2; ++ks) {
            short8 ah[2], al[2], bh[2], bl[2];
#pragma unroll
            for (int i = 0; i < 2; ++i) {
                ah[i] = *reinterpret_cast<const short8*>(&Ash[wm * 32 + i * 16 + l15][ks * 32 + quad * 8]);
                al[i] = *reinterpret_cast<const short8*>(&Asl[wm * 32 + i * 16 + l15][ks * 32 + quad * 8]);
            }
#pragma unroll
            for (int j = 0; j < 2; ++j) {
                bh[j] = *reinterpret_cast<const short8*>(&Bsh[wn * 32 + j * 16 + l15][ks * 32 + quad * 8]);
                bl[j] = *reinterpret_cast<const short8*>(&Bsl[wn * 32 + j * 16 + l15][ks * 32 + quad * 8]);
            }
#pragma unroll
            for (int i = 0; i < 2; ++i)
#pragma unroll
                for (int j = 0; j < 2; ++j) {
                    acc[i][j] = __builtin_amdgcn_mfma_f32_16x16x32_bf16(ah[i], bh[j], acc[i][j], 0, 0, 0);
                    acc[i][j] = __builtin_amdgcn_mfma_f32_16x16x32_bf16(ah[i], bl[j], acc[i][j], 0, 0, 0);
                    acc[i][j] = __builtin_amdgcn_mfma_f32_16x16x32_bf16(al[i], bh[j], acc[i][j], 0, 0, 0);
                }
        }
        __syncthreads();
    }
#pragma unroll
    for (int i = 0; i < 2; ++i)
#pragma unroll
        for (int j = 0; j < 2; ++j)
#pragma unroll
            for (int r = 0; r < 4; ++r)
                Gs[wm * 32 + i * 16 + quad * 4 + r][wn * 32 + j * 16 + l15] = acc[i][j][r];
    __syncthreads();
    {
        const int jl = t >> 2, q = t & 3;
        float cp = 0.f;
#pragma unroll
        for (int i = 0; i < 16; ++i) {
            const int d = q * 16 + i;
            cp += leakyf(Gs[jl][d]) * a21[d0 + d];
        }
        cp += __shfl_xor(cp, 1); cp += __shfl_xor(cp, 2);
        if (q == 0) atomicAdd(&cat[j0 + jl], cp);
    }
    {
        const int dl = t >> 2, q = t & 3;
        short8 pk0, pk1;
#pragma unroll
        for (int i = 0; i < 8; ++i) pk0[i] = f2b(Gs[q * 16 + i][dl]);
#pragma unroll
        for (int i = 0; i < 8; ++i) pk1[i] = f2b(Gs[q * 16 + 8 + i][dl]);
        short* gp = GT + (d0 + dl) * 4096 + j0 + q * 16;
        *reinterpret_cast<short8*>(gp) = pk0;
        *reinterpret_cast<short8*>(gp + 8) = pk1;
    }
}

// ---------------------------------------------------------------- edge weights
// Bmat[n,j] = H[n,j]*satexp(c_j + d_n) bf16; rowsum from ROUNDED values (consistency).
__global__ __launch_bounds__(256) void edge_weights(
        const float* __restrict__ H, const float* __restrict__ cat,
        const float* __restrict__ dn, short* __restrict__ Bmat,
        float* __restrict__ rsum) {
    const long n = blockIdx.x;
    const int t = threadIdx.x;
    const float dv = dn[n];
    const float* hp = H + n * 4096;
    short* bp = Bmat + n * 4096;
    float acc = 0.f;
#pragma unroll
    for (int c = 0; c < 4; ++c) {
        const int j = c * 1024 + t * 4;
        f32x4 h  = *reinterpret_cast<const f32x4*>(hp + j);
        f32x4 cv = *reinterpret_cast<const f32x4*>(cat + j);
        short4v pk;
#pragma unroll
        for (int k = 0; k < 4; ++k) {
            const float s = satexpf(cv[k] + dv) * h[k];
            const short sb = f2b(s);
            pk[k] = sb;
            acc += b2f(sb);
        }
        *reinterpret_cast<short4v*>(bp + j) = pk;
    }
#pragma unroll
    for (int m = 1; m < 64; m <<= 1) acc += __shfl_xor(acc, m);
    __shared__ float wsum[4];
    if ((t & 63) == 0) wsum[t >> 6] = acc;
    __syncthreads();
    if (t == 0) rsum[n] = wsum[0] + wsum[1] + wsum[2] + wsum[3];
}

// ---------------------------------------------------------------- launch
extern "C" void kernel_launch(void* const* d_in, const int* in_sizes, int n_in,
                              void* d_out, int out_size, void* d_ws, size_t ws_size,
                              hipStream_t stream) {
    const float* x   = (const float*)d_in[0];
    const float* H   = (const float*)d_in[1];
    const float* w1  = (const float*)d_in[2];
    const float* w2  = (const float*)d_in[3];
    const float* a1  = (const float*)d_in[4];
    const float* a21 = (const float*)d_in[5];
    const float* a22 = (const float*)d_in[6];
    float* out = (float*)d_out;
    char* ws = (char*)d_ws;

    // region0: xw1 fp32 [16384,256] (16.78MB), later C1p [4,4096,576] (37.75MB)
    float* xw1  = (float*)(ws + 0);
    float* C1p  = (float*)(ws + 0);
    short* yT   = (short*)(ws + 37748736);   // [576,16384] bf16
    float* dn   = (float*)(ws + 56623104);   // [16384]
    short* w1Th = (short*)(ws + 56688640);   // [256,256] bf16
    short* w1Tl = (short*)(ws + 56819712);
    short* w2Th = (short*)(ws + 56950784);
    short* w2Tl = (short*)(ws + 57081856);
    float* C1   = (float*)(ws + 57212928);   // [4096,288]
    short* GT   = (short*)(ws + 61931520);   // [256,4096] bf16
    float* cat  = (float*)(ws + 64028672);   // [4096]
    float* rsum = (float*)(ws + 64045056);   // [16384]
    short* HbT  = (short*)(ws + 64110592);   // [4096,16384] bf16 (128MB)
    short* Bmat = HbT;                        // reuse: HbT dead after C1 GEMM

    transpose_split<<<dim3(4, 4), 256, 0, stream>>>(w1, w1Th, w1Tl, 256, 256);
    transpose_split<<<dim3(4, 4), 256, 0, stream>>>(w2, w2Th, w2Tl, 256, 256);
    transpose_f32_bf16<<<dim3(256, 64), 256, 0, stream>>>(H, HbT, 16384, 4096);

    // xw1 = x @ w1 (split-bf16, ~fp32 accurate)
    gemm_xw1<<<dim3(128, 4), 256, 0, stream>>>(x, w1Th, w1Tl, xw1);

    // g, d, yT (hi+lo)
    node_stats<<<dim3(256), 256, 0, stream>>>(xw1, a1, a22, yT, dn);

    // C1[j,:] (split-K=4 partials over z, N=576 hi|lo)
    gemm_bt<128, 96, 0><<<dim3(32, 6, 4), 256, 0, stream>>>(
            HbT, yT, C1p, 16384, 16384, 576, 4096, nullptr, (long)4096 * 576);
    reduce_C1<<<dim3(4608), 256, 0, stream>>>(C1p, C1);

    // G = f2@w2 (split) -> GT bf16, c_j (fp32 path)
    hipMemsetAsync(cat, 0, 4096 * sizeof(float), stream);
    gemm_G<<<dim3(64, 4), 256, 0, stream>>>(C1, w2Th, w2Tl, a21, GT, cat);

    // Bmat + rowsum
    edge_weights<<<dim3(16384), 256, 0, stream>>>(H, cat, dn, Bmat, rsum);

    // out = leaky((Bmat @ G) / rowsum)
    gemm_bt<128, 64, 2><<<dim3(128, 4, 1), 256, 0, stream>>>(
            Bmat, GT, out, 4096, 4096, 256, 4096, rsum, 0);
}

// Round 4
// 673.326 us; speedup vs baseline: 1.0797x; 1.0797x over previous
//
#include <hip/hip_runtime.h>

// HyperGAT layer, N=16384, E=4096, D=256 on gfx950.
//   xw1 = x@w1 (split-bf16 MFMA, ~fp32 accurate)
//   g_n = satexp(leaky(xw1)@a1), d_n = leaky(xw1)@a22
//   y = g*xw1 quantized to i16 (per-dd global scale), split qh/ql i8 planes
//   C1 = H^T @ [qh|ql]  (i8 MFMA, exact int accum; reconstruct with scales)
//   f2 = leaky(C1/den);  G = f2@w2 (split);  c_j = leaky(G)@a21
//   Bmat[n,j] = Hbit*satexp(c_j+d_n) bf16 (H read as packed bits, L2-resident)
//   out = leaky((Bmat@G)/rowsum)

typedef __attribute__((ext_vector_type(8))) short short8;
typedef __attribute__((ext_vector_type(4))) float f32x4;
typedef __attribute__((ext_vector_type(4))) int int4v;
typedef __attribute__((ext_vector_type(4))) unsigned int uint4v;

__device__ __forceinline__ float leakyf(float v) { return v > 0.f ? v : 0.1f * v; }
__device__ __forceinline__ float fastrcp(float x) { return __builtin_amdgcn_rcpf(x); }

// exp(8*tanh(t/8)), branchless, overflow-safe
__device__ __forceinline__ float satexpf(float t) {
    float u = fminf(fmaxf(t * 0.25f, -30.f), 30.f);
    float p = __expf(u);
    float th = (p - 1.f) * fastrcp(p + 1.f);
    return __expf(8.f * th);
}

__device__ __forceinline__ short f2b(float v) {
    unsigned int x = __float_as_uint(v);
    x += 0x7fffu + ((x >> 16) & 1u);
    return (short)(x >> 16);
}
__device__ __forceinline__ float b2f(short s) {
    return __uint_as_float(((unsigned int)(unsigned short)s) << 16);
}

// ---------------------------------------------------------------- weight transpose + hi/lo split
__global__ __launch_bounds__(256) void transpose_split(
        const float* __restrict__ src, short* __restrict__ dh,
        short* __restrict__ dl, int R, int C) {
    __shared__ float Ts[64][65];
    const int t = threadIdx.x;
    const long r0 = (long)blockIdx.x * 64;
    const long c0 = (long)blockIdx.y * 64;
    {
        const int row = t >> 2, cc = (t & 3) * 16;
        const float* p = src + (r0 + row) * (long)C + c0 + cc;
#pragma unroll
        for (int i = 0; i < 4; ++i) {
            f32x4 v = *reinterpret_cast<const f32x4*>(p + i * 4);
#pragma unroll
            for (int k = 0; k < 4; ++k) Ts[row][cc + i * 4 + k] = v[k];
        }
    }
    __syncthreads();
    {
        const int cl = t >> 2, ch = (t & 3) * 16;
        short8 h0, h1, l0, l1;
#pragma unroll
        for (int i = 0; i < 8; ++i) {
            float v = Ts[ch + i][cl];
            short h = f2b(v);
            h0[i] = h; l0[i] = f2b(v - b2f(h));
        }
#pragma unroll
        for (int i = 0; i < 8; ++i) {
            float v = Ts[ch + 8 + i][cl];
            short h = f2b(v);
            h1[i] = h; l1[i] = f2b(v - b2f(h));
        }
        short* qh = dh + (c0 + cl) * (long)R + r0 + ch;
        short* ql = dl + (c0 + cl) * (long)R + r0 + ch;
        *reinterpret_cast<short8*>(qh) = h0;
        *reinterpret_cast<short8*>(qh + 8) = h1;
        *reinterpret_cast<short8*>(ql) = l0;
        *reinterpret_cast<short8*>(ql + 8) = l1;
    }
}

// ---------------------------------------------------------------- H: fp32 [16384,4096] -> HbT i8 [4096,16384] + Hbits u32 [16384,128]
__global__ __launch_bounds__(256) void transposeH_pack(
        const float* __restrict__ H, char* __restrict__ HbT,
        unsigned int* __restrict__ Hbits) {
    __shared__ float Ts[64][65];
    const int t = threadIdx.x;
    const long r0 = (long)blockIdx.x * 64;   // n
    const long c0 = (long)blockIdx.y * 64;   // j
    {
        const int row = t >> 2, cc = (t & 3) * 16;
        const float* p = H + (r0 + row) * 4096L + c0 + cc;
#pragma unroll
        for (int i = 0; i < 4; ++i) {
            f32x4 v = *reinterpret_cast<const f32x4*>(p + i * 4);
#pragma unroll
            for (int k = 0; k < 4; ++k) Ts[row][cc + i * 4 + k] = v[k];
        }
    }
    __syncthreads();
    // HbT i8: thread -> (j-local cl, 16-n chunk ch)
    {
        const int cl = t >> 2, ch = (t & 3) * 16;
        uint4v pk;
#pragma unroll
        for (int wv = 0; wv < 4; ++wv) {
            unsigned int u = 0;
#pragma unroll
            for (int b = 0; b < 4; ++b)
                u |= (Ts[ch + wv * 4 + b][cl] != 0.f ? 1u : 0u) << (8 * b);
            pk[wv] = u;
        }
        *reinterpret_cast<uint4v*>(HbT + (c0 + cl) * 16384L + r0 + ch) = pk;
    }
    // Hbits row-major: thread t<128 -> (n-local nl, word w)
    if (t < 128) {
        const int nl = t >> 1, w = t & 1;
        unsigned int u = 0;
#pragma unroll
        for (int b = 0; b < 32; ++b)
            u |= (Ts[nl][w * 32 + b] != 0.f ? 1u : 0u) << b;
        Hbits[(r0 + nl) * 128 + (c0 >> 5) + w] = u;
    }
}

// ---------------------------------------------------------------- xw1 split GEMM (fp32-accurate)
__global__ __launch_bounds__(256) void gemm_xw1(
        const float* __restrict__ A, const short* __restrict__ Bh,
        const short* __restrict__ Bl, float* __restrict__ C) {
    __shared__ short Ash[128][72];
    __shared__ short Asl[128][72];
    __shared__ short Bsh[64][72];
    __shared__ short Bsl[64][72];
    const int t = threadIdx.x;
    const int wid = t >> 6, lane = t & 63;
    const int wm = wid & 1, wn = wid >> 1;
    const int quad = lane >> 4, l15 = lane & 15;
    const long m0 = (long)blockIdx.x * 128;
    const long n0 = (long)blockIdx.y * 64;
    f32x4 acc[4][2];
#pragma unroll
    for (int i = 0; i < 4; ++i)
#pragma unroll
        for (int j = 0; j < 2; ++j)
#pragma unroll
            for (int r = 0; r < 4; ++r) acc[i][j][r] = 0.f;

    for (int kb = 0; kb < 256; kb += 64) {
#pragma unroll
        for (int it = 0; it < 4; ++it) {
            const int cid = t + it * 256;
            const int row = cid >> 3, c8 = (cid & 7) * 8;
            const float* ap = A + (m0 + row) * 256 + kb + c8;
            f32x4 v0 = *reinterpret_cast<const f32x4*>(ap);
            f32x4 v1 = *reinterpret_cast<const f32x4*>(ap + 4);
            short8 hi, lo;
#pragma unroll
            for (int k = 0; k < 4; ++k) {
                short h0 = f2b(v0[k]); hi[k] = h0; lo[k] = f2b(v0[k] - b2f(h0));
                short h1 = f2b(v1[k]); hi[4 + k] = h1; lo[4 + k] = f2b(v1[k] - b2f(h1));
            }
            *reinterpret_cast<short8*>(&Ash[row][c8]) = hi;
            *reinterpret_cast<short8*>(&Asl[row][c8]) = lo;
        }
#pragma unroll
        for (int it = 0; it < 2; ++it) {
            const int cid = t + it * 256;
            const int row = cid >> 3, c8 = (cid & 7) * 8;
            *reinterpret_cast<short8*>(&Bsh[row][c8]) =
                *reinterpret_cast<const short8*>(Bh + (n0 + row) * 256 + kb + c8);
            *reinterpret_cast<short8*>(&Bsl[row][c8]) =
                *reinterpret_cast<const short8*>(Bl + (n0 + row) * 256 + kb + c8);
        }
        __syncthreads();
#pragma unroll
        for (int ks = 0; ks < 2; ++ks) {
            short8 ah[4], al[4], bh[2], bl[2];
#pragma unroll
            for (int i = 0; i < 4; ++i) {
                ah[i] = *reinterpret_cast<const short8*>(&Ash[wm * 64 + i * 16 + l15][ks * 32 + quad * 8]);
                al[i] = *reinterpret_cast<const short8*>(&Asl[wm * 64 + i * 16 + l15][ks * 32 + quad * 8]);
            }
#pragma unroll
            for (int j = 0; j < 2; ++j) {
                bh[j] = *reinterpret_cast<const short8*>(&Bsh[wn * 32 + j * 16 + l15][ks * 32 + quad * 8]);
                bl[j] = *reinterpret_cast<const short8*>(&Bsl[wn * 32 + j * 16 + l15][ks * 32 + quad * 8]);
            }
#pragma unroll
            for (int i = 0; i < 4; ++i)
#pragma unroll
                for (int j = 0; j < 2; ++j) {
                    acc[i][j] = __builtin_amdgcn_mfma_f32_16x16x32_bf16(ah[i], bh[j], acc[i][j], 0, 0, 0);
                    acc[i][j] = __builtin_amdgcn_mfma_f32_16x16x32_bf16(ah[i], bl[j], acc[i][j], 0, 0, 0);
                    acc[i][j] = __builtin_amdgcn_mfma_f32_16x16x32_bf16(al[i], bh[j], acc[i][j], 0, 0, 0);
                }
        }
        __syncthreads();
    }
#pragma unroll
    for (int i = 0; i < 4; ++i) {
        const long grow = m0 + wm * 64 + i * 16 + quad * 4;
#pragma unroll
        for (int j = 0; j < 2; ++j) {
            const long gcol = n0 + wn * 32 + j * 16 + l15;
#pragma unroll
            for (int r = 0; r < 4; ++r)
                C[(grow + r) * 256 + gcol] = acc[i][j][r];
        }
    }
}

// ---------------------------------------------------------------- node stats: g, dn, per-dd |y| max
__global__ __launch_bounds__(256) void node_stats1(
        const float* __restrict__ xw1, const float* __restrict__ a1,
        const float* __restrict__ a22, float* __restrict__ g_out,
        float* __restrict__ dn, unsigned int* __restrict__ ddmax) {
    __shared__ float Mx[4][260];
    const int t = threadIdx.x;
    const int n0 = blockIdx.x * 64;
    const int r = t >> 2, q = t & 3;
    const long n = n0 + r;
    const float* xp = xw1 + n * 256 + q * 64;
    float vals[64];
    float facc = 0.f, dacc = 0.f;
#pragma unroll
    for (int i = 0; i < 16; ++i) {
        f32x4 v  = *reinterpret_cast<const f32x4*>(xp + i * 4);
        f32x4 b1 = *reinterpret_cast<const f32x4*>(a1 + q * 64 + i * 4);
        f32x4 b2 = *reinterpret_cast<const f32x4*>(a22 + q * 64 + i * 4);
#pragma unroll
        for (int k = 0; k < 4; ++k) {
            float lv = leakyf(v[k]);
            facc += lv * b1[k];
            dacc += lv * b2[k];
            vals[i * 4 + k] = v[k];
        }
    }
    facc += __shfl_xor(facc, 1); facc += __shfl_xor(facc, 2);
    dacc += __shfl_xor(dacc, 1); dacc += __shfl_xor(dacc, 2);
    const float g = satexpf(facc);
    if (q == 0) { dn[n] = dacc; g_out[n] = g; }
    // per-dd |y| max over the wave's 16 rows (lane = (r%16)*4 + q)
    float lm[64];
#pragma unroll
    for (int i = 0; i < 64; ++i) lm[i] = fabsf(vals[i] * g);
#pragma unroll
    for (int m = 4; m < 64; m <<= 1)
#pragma unroll
        for (int i = 0; i < 64; ++i) lm[i] = fmaxf(lm[i], __shfl_xor(lm[i], m));
    float gm = g;
#pragma unroll
    for (int m = 1; m < 64; m <<= 1) gm = fmaxf(gm, __shfl_xor(gm, m));
    const int wv = t >> 6, lane = t & 63;
    if (lane < 4) {
#pragma unroll
        for (int i = 0; i < 64; ++i) Mx[wv][lane * 64 + i] = lm[i];
    }
    if (lane == 0) Mx[wv][256] = gm;
    __syncthreads();
    if (t < 256) {
        float m = fmaxf(fmaxf(Mx[0][t], Mx[1][t]), fmaxf(Mx[2][t], Mx[3][t]));
        atomicMax(&ddmax[t], __float_as_uint(m));
    }
    // BUGFIX (round 3): block has 256 threads, so "t < 257" never covered
    // index 256 -> ddmax[256]=0 -> den scale 0 -> rcp(0)=inf -> NaN cascade.
    if (t == 0) {
        float m = fmaxf(fmaxf(Mx[0][256], Mx[1][256]), fmaxf(Mx[2][256], Mx[3][256]));
        atomicMax(&ddmax[256], __float_as_uint(m));
    }
}

// ---------------------------------------------------------------- quantize y -> yQ i8 [576,16384] (hi rows 0..287, lo 288..575)
__global__ __launch_bounds__(256) void quantize_y(
        const float* __restrict__ xw1, const float* __restrict__ g_in,
        const unsigned int* __restrict__ ddmax, char* __restrict__ yQ) {
    __shared__ unsigned int Qh[257][16];
    __shared__ unsigned int Ql[257][16];
    const int t = threadIdx.x;
    const int n0 = blockIdx.x * 64;
    const int dd0 = (t >> 4) * 16;
    const int w = t & 15;
    const int r4 = w * 4;
    float s[16];
#pragma unroll
    for (int i = 0; i < 16; ++i)
        s[i] = 32512.f / __uint_as_float(ddmax[dd0 + i]);
    const float sg = 32512.f / __uint_as_float(ddmax[256]);
    unsigned int bh[16], bl[16];
#pragma unroll
    for (int i = 0; i < 16; ++i) { bh[i] = 0u; bl[i] = 0u; }
    unsigned int gh = 0u, gl = 0u;
#pragma unroll
    for (int rr = 0; rr < 4; ++rr) {
        const long n = n0 + r4 + rr;
        const float gg = g_in[n];
        const float* xp = xw1 + n * 256 + dd0;
#pragma unroll
        for (int c = 0; c < 4; ++c) {
            f32x4 v = *reinterpret_cast<const f32x4*>(xp + c * 4);
#pragma unroll
            for (int k = 0; k < 4; ++k) {
                const int i = c * 4 + k;
                int qv = __float2int_rn(v[k] * gg * s[i]);
                qv = max(-32639, min(32639, qv));
                const int qh = (qv + 128) >> 8;
                const int ql = qv - (qh << 8);
                bh[i] |= ((unsigned int)(qh & 255)) << (8 * rr);
                bl[i] |= ((unsigned int)(ql & 255)) << (8 * rr);
            }
        }
        if (t < 16) {
            int qv = __float2int_rn(gg * sg);
            qv = max(-32639, min(32639, qv));
            const int qh = (qv + 128) >> 8;
            const int ql = qv - (qh << 8);
            gh |= ((unsigned int)(qh & 255)) << (8 * rr);
            gl |= ((unsigned int)(ql & 255)) << (8 * rr);
        }
    }
#pragma unroll
    for (int i = 0; i < 16; ++i) { Qh[dd0 + i][w] = bh[i]; Ql[dd0 + i][w] = bl[i]; }
    if (t < 16) { Qh[256][t] = gh; Ql[256][t] = gl; }
    __syncthreads();
#pragma unroll
    for (int it = 0; it < 2; ++it) {
        const int dd = it * 256 + t;
        if (dd < 288) {
#pragma unroll
            for (int s2 = 0; s2 < 4; ++s2) {
                uint4v vh, vl;
                if (dd < 257) {
                    vh = *reinterpret_cast<const uint4v*>(&Qh[dd][s2 * 4]);
                    vl = *reinterpret_cast<const uint4v*>(&Ql[dd][s2 * 4]);
                } else {
#pragma unroll
                    for (int k = 0; k < 4; ++k) { vh[k] = 0u; vl[k] = 0u; }
                }
                *reinterpret_cast<uint4v*>(yQ + (long)dd * 16384 + n0 + s2 * 16) = vh;
                *reinterpret_cast<uint4v*>(yQ + (long)(288 + dd) * 16384 + n0 + s2 * 16) = vl;
            }
        }
    }
}

// ---------------------------------------------------------------- C1 GEMM, i8 MFMA 16x16x64
// A = HbT i8 [4096,16384], B = yQ i8 [576,16384], Cp i32 [4][4096][576]
// BM=128 (j), BN=96 (dd), BK=128, grid (32, 6, 4)
__global__ __launch_bounds__(256) void gemm_c1_i8(
        const char* __restrict__ Ab, const char* __restrict__ Bb,
        int* __restrict__ Cp) {
    __shared__ char As[128][144];
    __shared__ char Bs[96][144];
    const int t = threadIdx.x;
    const int wid = t >> 6, lane = t & 63;
    const int wm = wid & 1, wn = wid >> 1;
    const int quad = lane >> 4, l15 = lane & 15;
    const long m0 = (long)blockIdx.x * 128;
    const long n0 = (long)blockIdx.y * 96;
    const long k0 = (long)blockIdx.z * 4096;
    int* Cz = Cp + (long)blockIdx.z * (4096L * 576);
    int4v acc[4][3];
#pragma unroll
    for (int i = 0; i < 4; ++i)
#pragma unroll
        for (int j = 0; j < 3; ++j)
#pragma unroll
            for (int r = 0; r < 4; ++r) acc[i][j][r] = 0;

    for (int kb = 0; kb < 4096; kb += 128) {
        // A: 128 rows x 128B = 1024 x 16B chunks
#pragma unroll
        for (int it = 0; it < 4; ++it) {
            const int cid = t + it * 256;
            const int row = cid >> 3, seg = (cid & 7) * 16;
            *reinterpret_cast<uint4v*>(&As[row][seg]) =
                *reinterpret_cast<const uint4v*>(Ab + (m0 + row) * 16384 + k0 + kb + seg);
        }
        // B: 96 rows x 128B = 768 x 16B chunks
#pragma unroll
        for (int it = 0; it < 3; ++it) {
            const int cid = t + it * 256;
            const int row = cid >> 3, seg = (cid & 7) * 16;
            *reinterpret_cast<uint4v*>(&Bs[row][seg]) =
                *reinterpret_cast<const uint4v*>(Bb + (n0 + row) * 16384 + k0 + kb + seg);
        }
        __syncthreads();
#pragma unroll
        for (int ks = 0; ks < 2; ++ks) {
            int4v af[4], bf[3];
#pragma unroll
            for (int i = 0; i < 4; ++i)
                af[i] = *reinterpret_cast<const int4v*>(
                        &As[wm * 64 + i * 16 + l15][ks * 64 + quad * 16]);
#pragma unroll
            for (int j = 0; j < 3; ++j)
                bf[j] = *reinterpret_cast<const int4v*>(
                        &Bs[wn * 48 + j * 16 + l15][ks * 64 + quad * 16]);
#pragma unroll
            for (int i = 0; i < 4; ++i)
#pragma unroll
                for (int j = 0; j < 3; ++j)
                    acc[i][j] = __builtin_amdgcn_mfma_i32_16x16x64_i8(
                            af[i], bf[j], acc[i][j], 0, 0, 0);
        }
        __syncthreads();
    }
#pragma unroll
    for (int i = 0; i < 4; ++i) {
        const long grow = m0 + wm * 64 + i * 16 + quad * 4;
#pragma unroll
        for (int j = 0; j < 3; ++j) {
            const long gcol = n0 + wn * 48 + j * 16 + l15;
#pragma unroll
            for (int r = 0; r < 4; ++r)
                Cz[(grow + r) * 576 + gcol] = acc[i][j][r];
        }
    }
}

// ---------------------------------------------------------------- reduce partials + reconstruct scales
__global__ __launch_bounds__(256) void reduce_C1(
        const int* __restrict__ C1p, const unsigned int* __restrict__ ddmax,
        float* __restrict__ C1) {
    const int i = blockIdx.x * 256 + threadIdx.x;   // < 4096*288
    const int j = i / 288, dd = i - j * 288;
    const int* p = C1p + (long)j * 576 + dd;
    int sh = 0, sl = 0;
#pragma unroll
    for (int z = 0; z < 4; ++z) {
        const int* pz = p + (long)z * 4096 * 576;
        sh += pz[0]; sl += pz[288];
    }
    const float scale = __uint_as_float(ddmax[dd]) * (1.f / 32512.f);
    C1[i] = (float)(sh * 256 + sl) * scale;
}

// ---------------------------------------------------------------- G = f2@w2 split (+ GT bf16, c_j)
__global__ __launch_bounds__(256) void gemm_G(
        const float* __restrict__ C1, const short* __restrict__ w2Th,
        const short* __restrict__ w2Tl, const float* __restrict__ a21,
        short* __restrict__ GT, float* __restrict__ cat) {
    __shared__ short Ash[64][72];
    __shared__ short Asl[64][72];
    __shared__ short Bsh[64][72];
    __shared__ short Bsl[64][72];
    __shared__ float Gs[64][65];
    const int t = threadIdx.x;
    const int wid = t >> 6, lane = t & 63;
    const int wm = wid & 1, wn = wid >> 1;
    const int quad = lane >> 4, l15 = lane & 15;
    const long j0 = (long)blockIdx.x * 64;
    const long d0 = (long)blockIdx.y * 64;
    f32x4 acc[2][2];
#pragma unroll
    for (int i = 0; i < 2; ++i)
#pragma unroll
        for (int j = 0; j < 2; ++j)
#pragma unroll
            for (int r = 0; r < 4; ++r) acc[i][j][r] = 0.f;

    for (int kb = 0; kb < 256; kb += 64) {
#pragma unroll
        for (int it = 0; it < 2; ++it) {
            const int cid = t + it * 256;
            const int row = cid >> 3, c8 = (cid & 7) * 8;
            const float rd = fastrcp(C1[(j0 + row) * 288 + 256]);
            const float* ap = C1 + (j0 + row) * 288 + kb + c8;
            f32x4 v0 = *reinterpret_cast<const f32x4*>(ap);
            f32x4 v1 = *reinterpret_cast<const f32x4*>(ap + 4);
            short8 hi, lo;
#pragma unroll
            for (int k = 0; k < 4; ++k) {
                float f0 = leakyf(v0[k] * rd);
                float f1 = leakyf(v1[k] * rd);
                short h0 = f2b(f0); hi[k] = h0; lo[k] = f2b(f0 - b2f(h0));
                short h1 = f2b(f1); hi[4 + k] = h1; lo[4 + k] = f2b(f1 - b2f(h1));
            }
            *reinterpret_cast<short8*>(&Ash[row][c8]) = hi;
            *reinterpret_cast<short8*>(&Asl[row][c8]) = lo;
            *reinterpret_cast<short8*>(&Bsh[row][c8]) =
                *reinterpret_cast<const short8*>(w2Th + (d0 + row) * 256 + kb + c8);
            *reinterpret_cast<short8*>(&Bsl[row][c8]) =
                *reinterpret_cast<const short8*>(w2Tl + (d0 + row) * 256 + kb + c8);
        }
        __syncthreads();
#pragma unroll
        for (int ks = 0; ks < 2; ++ks) {
            short8 ah[2], al[2], bh[2], bl[2];
#pragma unroll
            for (int i = 0; i < 2; ++i) {
                ah[i] = *reinterpret_cast<const short8*>(&Ash[wm * 32 + i * 16 + l15][ks * 32 + quad * 8]);
                al[i] = *reinterpret_cast<const short8*>(&Asl[wm * 32 + i * 16 + l15][ks * 32 + quad * 8]);
            }
#pragma unroll
            for (int j = 0; j < 2; ++j) {
                bh[j] = *reinterpret_cast<const short8*>(&Bsh[wn * 32 + j * 16 + l15][ks * 32 + quad * 8]);
                bl[j] = *reinterpret_cast<const short8*>(&Bsl[wn * 32 + j * 16 + l15][ks * 32 + quad * 8]);
            }
#pragma unroll
            for (int i = 0; i < 2; ++i)
#pragma unroll
                for (int j = 0; j < 2; ++j) {
                    acc[i][j] = __builtin_amdgcn_mfma_f32_16x16x32_bf16(ah[i], bh[j], acc[i][j], 0, 0, 0);
                    acc[i][j] = __builtin_amdgcn_mfma_f32_16x16x32_bf16(ah[i], bl[j], acc[i][j], 0, 0, 0);
                    acc[i][j] = __builtin_amdgcn_mfma_f32_16x16x32_bf16(al[i], bh[j], acc[i][j], 0, 0, 0);
                }
        }
        __syncthreads();
    }
#pragma unroll
    for (int i = 0; i < 2; ++i)
#pragma unroll
        for (int j = 0; j < 2; ++j)
#pragma unroll
            for (int r = 0; r < 4; ++r)
                Gs[wm * 32 + i * 16 + quad * 4 + r][wn * 32 + j * 16 + l15] = acc[i][j][r];
    __syncthreads();
    {
        const int jl = t >> 2, q = t & 3;
        float cp = 0.f;
#pragma unroll
        for (int i = 0; i < 16; ++i) {
            const int d = q * 16 + i;
            cp += leakyf(Gs[jl][d]) * a21[d0 + d];
        }
        cp += __shfl_xor(cp, 1); cp += __shfl_xor(cp, 2);
        if (q == 0) atomicAdd(&cat[j0 + jl], cp);
    }
    {
        const int dl = t >> 2, q = t & 3;
        short8 pk0, pk1;
#pragma unroll
        for (int i = 0; i < 8; ++i) pk0[i] = f2b(Gs[q * 16 + i][dl]);
#pragma unroll
        for (int i = 0; i < 8; ++i) pk1[i] = f2b(Gs[q * 16 + 8 + i][dl]);
        short* gp = GT + (d0 + dl) * 4096 + j0 + q * 16;
        *reinterpret_cast<short8*>(gp) = pk0;
        *reinterpret_cast<short8*>(gp + 8) = pk1;
    }
}

// ---------------------------------------------------------------- edge weights from packed bits
__global__ __launch_bounds__(256) void edge_weights(
        const unsigned int* __restrict__ Hbits, const float* __restrict__ cat,
        const float* __restrict__ dn, short* __restrict__ Bmat,
        float* __restrict__ rsum) {
    const long n = blockIdx.x;
    const int t = threadIdx.x;
    const float dv = dn[n];
    const unsigned int w = Hbits[n * 128 + (t >> 1)];
    const int bo = (t & 1) * 16;
    short* bp = Bmat + n * 4096 + t * 16;
    float acc = 0.f;
    short8 pk0, pk1;
#pragma unroll
    for (int c = 0; c < 4; ++c) {
        f32x4 cv = *reinterpret_cast<const f32x4*>(cat + t * 16 + c * 4);
#pragma unroll
        for (int k = 0; k < 4; ++k) {
            const int kk = c * 4 + k;
            const float s = ((w >> (bo + kk)) & 1u) ? satexpf(cv[k] + dv) : 0.f;
            const short sb = f2b(s);
            if (kk < 8) pk0[kk] = sb; else pk1[kk - 8] = sb;
            acc += b2f(sb);
        }
    }
    *reinterpret_cast<short8*>(bp) = pk0;
    *reinterpret_cast<short8*>(bp + 8) = pk1;
#pragma unroll
    for (int m = 1; m < 64; m <<= 1) acc += __shfl_xor(acc, m);
    __shared__ float wsum[4];
    if ((t & 63) == 0) wsum[t >> 6] = acc;
    __syncthreads();
    if (t == 0) rsum[n] = wsum[0] + wsum[1] + wsum[2] + wsum[3];
}

// ---------------------------------------------------------------- final GEMM (bf16, B^T), epilogue leaky(v/rsum)
template<int BM, int BN>
__global__ __launch_bounds__(256) void gemm_final(
        const short* __restrict__ Ab, const short* __restrict__ Bb,
        float* __restrict__ C, const float* __restrict__ aux) {
    constexpr int BK = 64;
    constexpr int TM = BM / 32, TN = BN / 32;
    __shared__ short As[BM][BK + 8];
    __shared__ short Bs[BN][BK + 8];
    const int t = threadIdx.x;
    const int wid = t >> 6, lane = t & 63;
    const int wm = wid & 1, wn = wid >> 1;
    const int quad = lane >> 4, l15 = lane & 15;
    const long m0 = (long)blockIdx.x * BM;
    const long n0 = (long)blockIdx.y * BN;
    f32x4 acc[TM][TN];
#pragma unroll
    for (int i = 0; i < TM; ++i)
#pragma unroll
        for (int j = 0; j < TN; ++j)
#pragma unroll
            for (int r = 0; r < 4; ++r) acc[i][j][r] = 0.f;

    for (int kb = 0; kb < 4096; kb += BK) {
#pragma unroll
        for (int it = 0; it < BM * BK / 2048; ++it) {
            const int cid = t + it * 256;
            const int row = cid >> 3, c8 = (cid & 7) * 8;
            *reinterpret_cast<short8*>(&As[row][c8]) =
                *reinterpret_cast<const short8*>(Ab + (m0 + row) * 4096 + kb + c8);
        }
#pragma unroll
        for (int it = 0; it < BN * BK / 2048; ++it) {
            const int cid = t + it * 256;
            const int row = cid >> 3, c8 = (cid & 7) * 8;
            *reinterpret_cast<short8*>(&Bs[row][c8]) =
                *reinterpret_cast<const short8*>(Bb + (n0 + row) * 4096 + kb + c8);
        }
        __syncthreads();
#pragma unroll
        for (int ks = 0; ks < 2; ++ks) {
            short8 af[TM], bf[TN];
#pragma unroll
            for (int i = 0; i < TM; ++i)
                af[i] = *reinterpret_cast<const short8*>(
                        &As[wm * (BM / 2) + i * 16 + l15][ks * 32 + quad * 8]);
#pragma unroll
            for (int j = 0; j < TN; ++j)
                bf[j] = *reinterpret_cast<const short8*>(
                        &Bs[wn * (BN / 2) + j * 16 + l15][ks * 32 + quad * 8]);
#pragma unroll
            for (int i = 0; i < TM; ++i)
#pragma unroll
                for (int j = 0; j < TN; ++j)
                    acc[i][j] = __builtin_amdgcn_mfma_f32_16x16x32_bf16(
                            af[i], bf[j], acc[i][j], 0, 0, 0);
        }
        __syncthreads();
    }
#pragma unroll
    for (int i = 0; i < TM; ++i) {
        const long grow = m0 + wm * (BM / 2) + i * 16 + quad * 4;
#pragma unroll
        for (int j = 0; j < TN; ++j) {
            const long gcol = n0 + wn * (BN / 2) + j * 16 + l15;
#pragma unroll
            for (int r = 0; r < 4; ++r)
                C[(grow + r) * 256 + gcol] =
                    leakyf(acc[i][j][r] * fastrcp(aux[grow + r]));
        }
    }
}

// ---------------------------------------------------------------- launch
extern "C" void kernel_launch(void* const* d_in, const int* in_sizes, int n_in,
                              void* d_out, int out_size, void* d_ws, size_t ws_size,
                              hipStream_t stream) {
    const float* x   = (const float*)d_in[0];
    const float* H   = (const float*)d_in[1];
    const float* w1  = (const float*)d_in[2];
    const float* w2  = (const float*)d_in[3];
    const float* a1  = (const float*)d_in[4];
    const float* a21 = (const float*)d_in[5];
    const float* a22 = (const float*)d_in[6];
    float* out = (float*)d_out;
    char* ws = (char*)d_ws;

    // region0 [0,128MB): xw1 fp32 (16.8MB) -> C1p i32 (37.75MB) -> Bmat bf16 (128MB)
    // HbT i8 lives in [64MB,128MB) until C1 GEMM done (disjoint from xw1/C1p).
    float* xw1   = (float*)(ws + 0);
    int*   C1p   = (int*)(ws + 0);
    short* Bmat  = (short*)(ws + 0);
    char*  HbT   = (char*)(ws + 67108864);
    char*  yQ    = (char*)(ws + 134217728);               // [576,16384] i8
    float* dn    = (float*)(ws + 143654912);              // [16384]
    float* g     = (float*)(ws + 143720448);              // [16384]
    unsigned int* ddmax = (unsigned int*)(ws + 143785984);// [288]
    short* w1Th  = (short*)(ws + 143790080);
    short* w1Tl  = (short*)(ws + 143921152);
    short* w2Th  = (short*)(ws + 144052224);
    short* w2Tl  = (short*)(ws + 144183296);
    float* C1    = (float*)(ws + 144314368);              // [4096,288]
    short* GT    = (short*)(ws + 149032960);              // [256,4096] bf16
    float* cat   = (float*)(ws + 151130112);              // [4096]
    float* rsum  = (float*)(ws + 151146496);              // [16384]
    unsigned int* Hbits = (unsigned int*)(ws + 151212032);// [16384,128]

    hipMemsetAsync(ddmax, 0, 288 * sizeof(unsigned int), stream);
    hipMemsetAsync(cat, 0, 4096 * sizeof(float), stream);

    transpose_split<<<dim3(4, 4), 256, 0, stream>>>(w1, w1Th, w1Tl, 256, 256);
    transpose_split<<<dim3(4, 4), 256, 0, stream>>>(w2, w2Th, w2Tl, 256, 256);
    transposeH_pack<<<dim3(256, 64), 256, 0, stream>>>(H, HbT, Hbits);

    gemm_xw1<<<dim3(128, 4), 256, 0, stream>>>(x, w1Th, w1Tl, xw1);
    node_stats1<<<dim3(256), 256, 0, stream>>>(xw1, a1, a22, g, dn, ddmax);
    quantize_y<<<dim3(256), 256, 0, stream>>>(xw1, g, ddmax, yQ);

    gemm_c1_i8<<<dim3(32, 6, 4), 256, 0, stream>>>(HbT, yQ, C1p);
    reduce_C1<<<dim3(4608), 256, 0, stream>>>(C1p, ddmax, C1);

    gemm_G<<<dim3(64, 4), 256, 0, stream>>>(C1, w2Th, w2Tl, a21, GT, cat);

    edge_weights<<<dim3(16384), 256, 0, stream>>>(Hbits, cat, dn, Bmat, rsum);

    gemm_final<64, 128><<<dim3(256, 2), 256, 0, stream>>>(Bmat, GT, out, rsum);
}